// Round 10
// baseline (128.055 us; speedup 1.0000x reference)
//
#include <hip/hip_runtime.h>
#include <hip/hip_fp16.h>

// MyEncoder: B=8, S=4096, E=128, D=24, fp32 in/out.
// out = softmax((xWq+bq)(xWk+bk)^T / sqrt(128)) (xWv+bv) Wo + bo
// bf16-MFMA pipeline: prep -> proj (QKV GEMM) -> attn (flash partials,
// K-split, 32x32x16 transposed scores, in-register P, MFMA-computed l)
// -> combine (sum fp16 partials + wO epilogue).
// Softmax without max-subtraction (scores tiny, shift-invariant) => K-split
// partials purely additive. exp2 with log2(e) folded into Q scale.
//
// attn math (per 32-key group g, keys bit-2<->3-swap-permuted at staging):
//   S^T[key][q] (32x32) = mfma32(A=K d0-15, B=Q d0-15) + mfma32(K d16-31, Q d16-31)
//   C layout: col=lane&31=q, row=(reg&3)+8*(reg>>2)+4*(lane>>5)=key-placement
//   P = exp2(S^T): C regs 0-7 -> PV#1 B-frag (keys 0-15 natural),
//                  C regs 8-15 -> PV#2 B-frag (keys 16-31 natural)
//   O^T[d][q] += mfma32(A=V^T natural, B=P)  ; V row d=24 = 1.0 => C reg 12
//   (half 0) = l. LDS frag reads per FLOP halved vs 16x16 (Q/P cover 32 q).

#define B_ 8
#define S_ 4096
#define E_ 128
#define D_ 24
#define N_ (B_ * S_)               // 32768 rows
#define SCALE 0.08838834764831845f // 1/sqrt(128)
#define LOG2E 1.4426950408889634f

#define TK 128                     // keys per LDS tile in attn
#define KS_STRIDE 40               // K_s row stride (shorts) = 5x16B (odd -> conflict-free)
#define VS_STRIDE 136              // V_s row stride (shorts) = 17x16B (odd -> conflict-free)
#define HS_STRIDE 40               // H_s row stride in combine
#define XS_STRIDE 136              // x_s row stride (bf16) in proj
#define OS_STRIDE 84               // out_s row stride (fp32) in proj

typedef __attribute__((ext_vector_type(8))) short bfrag;    // 8 bf16 = 4 VGPR
typedef __attribute__((ext_vector_type(4))) float ffrag;    // 4 fp32
typedef __attribute__((ext_vector_type(16))) float ffrag16; // 16 fp32 (32x32 C)

__device__ inline unsigned short f2bf(float f) {           // RNE fp32->bf16
    unsigned int x = __builtin_bit_cast(unsigned int, f);
    return (unsigned short)((x + 0x7fffu + ((x >> 16) & 1u)) >> 16);
}
// round-half-up bf16 pair pack: 2 int-adds + v_perm (validated r5-r8 on HW)
__device__ inline unsigned int pack2h(float a, float b) {
    unsigned int ua = __builtin_bit_cast(unsigned int, a) + 0x8000u;
    unsigned int ub = __builtin_bit_cast(unsigned int, b) + 0x8000u;
    return __builtin_amdgcn_perm(ub, ua, 0x07060302);      // [a.hi16 | b.hi16]
}
// fp16 pair pack, RTZ, single v_cvt_pkrtz_f16_f32
__device__ inline unsigned int packh16(float a, float b) {
    return __builtin_bit_cast(unsigned int, __builtin_amdgcn_cvt_pkrtz(a, b));
}

// ---------------- Kernel 0: weight prep (8 blocks) ----------------
__global__ __launch_bounds__(256) void prep_kernel(
    const float* __restrict__ wQ, const float* __restrict__ bQ,
    const float* __restrict__ wK, const float* __restrict__ bK,
    const float* __restrict__ wV, const float* __restrict__ bV,
    const float* __restrict__ wO,
    unsigned short* __restrict__ Wf, unsigned short* __restrict__ wOf,
    float* __restrict__ bqkv)
{
    const int gtid   = blockIdx.x * 256 + threadIdx.x;
    const int stride = gridDim.x * 256;
    const float qs = SCALE * LOG2E;
    for (int idx = gtid; idx < 4 * 5 * 512; idx += stride) {
        const int j    = idx & 7;
        const int lane = (idx >> 3) & 63;
        const int nt   = (idx >> 9) % 5;
        const int kt   = idx / 2560;
        const int n = nt * 16 + (lane & 15);
        const int k = kt * 32 + ((lane >> 4) << 3) + j;
        float v = 0.0f;
        if (n < 24)      v = wQ[k * 24 + n] * qs;
        else if (n < 48) v = wK[k * 24 + (n - 24)];
        else if (n < 72) v = wV[k * 24 + (n - 48)];
        Wf[idx] = f2bf(v);
    }
    for (int idx = gtid; idx < 8 * 512; idx += stride) {
        const int j    = idx & 7;
        const int lane = (idx >> 3) & 63;
        const int nt   = idx >> 9;
        const int k = ((lane >> 4) << 3) + j;
        const int e = nt * 16 + (lane & 15);
        wOf[idx] = (k < 24) ? f2bf(wO[k * 128 + e]) : (unsigned short)0;
    }
    if (gtid < 80) {
        float v = 0.0f;
        if (gtid < 24)      v = bQ[gtid] * qs;
        else if (gtid < 48) v = bK[gtid - 24];
        else if (gtid < 72) v = bV[gtid - 48];
        bqkv[gtid] = v;
    }
}

// ---------------- Kernel 1: QKV projection (MFMA) ----------------
__global__ __launch_bounds__(256) void proj_kernel(
    const float* __restrict__ x, const unsigned short* __restrict__ Wf,
    const float* __restrict__ bqkv,
    unsigned short* __restrict__ Qbf, unsigned short* __restrict__ Kbf,
    unsigned short* __restrict__ Vt)
{
    __shared__ float smem[64 * OS_STRIDE];          // 21504 B, dual-purpose
    unsigned short* xs = (unsigned short*)smem;     // [64][XS_STRIDE]
    float* os = smem;                               // [64][OS_STRIDE]

    const int tid  = threadIdx.x;
    const int lane = tid & 63;
    const int w    = tid >> 6;
    const int col  = lane & 15;
    const int quad = lane >> 4;
    const int rb   = blockIdx.x * 64;

    #pragma unroll
    for (int i = 0; i < 8; ++i) {
        const int idx = i * 256 + tid;
        const int row = idx >> 5, c4 = idx & 31;
        const float4 xv = *(const float4*)(x + (size_t)(rb + row) * 128 + c4 * 4);
        uint2 h;
        h.x = pack2h(xv.x, xv.y);
        h.y = pack2h(xv.z, xv.w);
        *(uint2*)(&xs[row * XS_STRIDE + c4 * 4]) = h;
    }

    bfrag Wfr[20];
    #pragma unroll
    for (int f = 0; f < 20; ++f)
        Wfr[f] = *(const bfrag*)(Wf + (f * 64 + lane) * 8);

    __syncthreads();

    ffrag acc[5];
    #pragma unroll
    for (int nt = 0; nt < 5; ++nt) acc[nt] = (ffrag){0.f, 0.f, 0.f, 0.f};

    #pragma unroll
    for (int kt = 0; kt < 4; ++kt) {
        const bfrag Af = *(const bfrag*)(&xs[(w * 16 + col) * XS_STRIDE + kt * 32 + quad * 8]);
        #pragma unroll
        for (int nt = 0; nt < 5; ++nt)
            acc[nt] = __builtin_amdgcn_mfma_f32_16x16x32_bf16(Af, Wfr[kt * 5 + nt], acc[nt], 0, 0, 0);
    }

    __syncthreads();

    #pragma unroll
    for (int nt = 0; nt < 5; ++nt) {
        const float bb = bqkv[nt * 16 + col];
        #pragma unroll
        for (int r = 0; r < 4; ++r)
            os[(w * 16 + quad * 4 + r) * OS_STRIDE + nt * 16 + col] = acc[nt][r] + bb;
    }
    __syncthreads();

    // Q (tid<128) / K (tid>=128): row-major bf16, cols padded to 32
    {
        const int half  = tid & 1;
        const int row   = (tid >> 1) & 63;
        const int isK   = tid >> 7;
        const int cbase = isK * 24;
        unsigned int pk[8];
        #pragma unroll
        for (int g = 0; g < 8; ++g) {
            const int c0 = half * 16 + g * 2;
            const float f0 = (c0     < 24) ? os[row * OS_STRIDE + cbase + c0]     : 0.0f;
            const float f1 = (c0 + 1 < 24) ? os[row * OS_STRIDE + cbase + c0 + 1] : 0.0f;
            pk[g] = pack2h(f0, f1);
        }
        unsigned short* dst = (isK ? Kbf : Qbf) + (size_t)(rb + row) * 32 + half * 16;
        *(uint4*)(dst)     = make_uint4(pk[0], pk[1], pk[2], pk[3]);
        *(uint4*)(dst + 8) = make_uint4(pk[4], pk[5], pk[6], pk[7]);
    }

    // Vt: transposed [b][d][s], 16B stores
    if (tid < 192) {
        const int d  = tid % 24;
        const int ch = tid / 24;
        unsigned int p[4];
        #pragma unroll
        for (int g = 0; g < 4; ++g) {
            const float f0 = os[(ch * 8 + g * 2 + 0) * OS_STRIDE + 48 + d];
            const float f1 = os[(ch * 8 + g * 2 + 1) * OS_STRIDE + 48 + d];
            p[g] = pack2h(f0, f1);
        }
        const int b = rb >> 12, s0 = rb & 4095;
        uint4* dst = (uint4*)(Vt + (((size_t)(b * 24 + d)) << 12) + s0 + ch * 8);
        *dst = make_uint4(p[0], p[1], p[2], p[3]);
    }
}

// ---------------- Kernel 2: flash attention partials (32x32x16) ----------
// Grid (N/256, nsp). 512 threads = 8 waves x 32 queries = 256 q/block.
// K staged with key -> row bit-2<->3 swap so exp'd C regs 0-7 / 8-15 pack
// directly into the two PV B-fragments with V in natural key order.
__global__ __launch_bounds__(512, 4) void attn_kernel(
    const unsigned short* __restrict__ Qbf, const unsigned short* __restrict__ Kbf,
    const unsigned short* __restrict__ Vt,
    __half* __restrict__ Opart, float* __restrict__ lpart)
{
    __shared__ unsigned short Ks[TK * KS_STRIDE];     // 10240 B
    __shared__ unsigned short Vs[32 * VS_STRIDE];     // 8704 B (rows 25-31 junk, contained)

    const int tid    = threadIdx.x;
    const int lane   = tid & 63;
    const int w      = tid >> 6;                      // 0..7
    const int q32    = lane & 31;                     // q within tile; also m-row idx
    const int h      = lane >> 5;                     // half
    const int blk    = blockIdx.x;                    // 0..N/256-1
    const int split  = blockIdx.y;
    const int nsp    = gridDim.y;
    const int kchunk = S_ / nsp;
    const int b      = blk >> 4;                      // 16 blocks per batch
    const int qbase  = blk * 256 + w * 32;

    // ones row d=24 (128 keys = 16 uint4); staging only touches rows 0..23
    if (tid < 16)
        *(uint4*)(&Vs[24 * VS_STRIDE + tid * 8]) =
            make_uint4(0x3F803F80u, 0x3F803F80u, 0x3F803F80u, 0x3F803F80u);

    // Q B-frags: B[k=d][n=q]: n=lane&31, k=h*8+j (+16 for second MFMA)
    const bfrag Qf0 = *(const bfrag*)(Qbf + (size_t)(qbase + q32) * 32 + h * 8);
    const bfrag Qf1 = *(const bfrag*)(Qbf + (size_t)(qbase + q32) * 32 + 16 + h * 8);

    ffrag16 O = {0.f,0.f,0.f,0.f,0.f,0.f,0.f,0.f,0.f,0.f,0.f,0.f,0.f,0.f,0.f,0.f};

    const unsigned short* Kbase = Kbf + ((size_t)(b * 4096) + split * kchunk) * 32;
    const unsigned short* Vbase = Vt + (size_t)(b * 24) * 4096 + split * kchunk;

    __syncthreads();   // ones row visible

    for (int kb = 0; kb < kchunk; kb += TK) {
        // K tile: key -> row swap of bits 2,3 within each 32-key group
        {
            const int key = tid >> 2, ch = tid & 3;
            const uint4 t4 = *(const uint4*)(Kbase + (size_t)(kb + key) * 32 + ch * 8);
            const int kl  = key & 31;
            const int row = (key & ~31) | (kl & 19) | ((kl & 4) << 1) | ((kl & 8) >> 1);
            *(uint4*)(&Ks[row * KS_STRIDE + ch * 8]) = t4;
        }
        // V tile: 24 d-rows x 128 keys, natural order
        if (tid < 384) {
            const int d = tid >> 4, ch = tid & 15;
            const uint4 t4 = *(const uint4*)(Vbase + (size_t)d * 4096 + kb + ch * 8);
            *(uint4*)(&Vs[d * VS_STRIDE + ch * 8]) = t4;
        }
        __syncthreads();

        #pragma unroll
        for (int g = 0; g < 4; ++g) {
            // S^T (32 keys x 32 q): A[m=key-row][k=d] = Ks, two d-halves
            const bfrag Kf0 = *(const bfrag*)(&Ks[(g * 32 + q32) * KS_STRIDE + h * 8]);
            const bfrag Kf1 = *(const bfrag*)(&Ks[(g * 32 + q32) * KS_STRIDE + 16 + h * 8]);
            ffrag16 S = {0.f,0.f,0.f,0.f,0.f,0.f,0.f,0.f,0.f,0.f,0.f,0.f,0.f,0.f,0.f,0.f};
            S = __builtin_amdgcn_mfma_f32_32x32x16_bf16(Kf0, Qf0, S, 0, 0, 0);
            S = __builtin_amdgcn_mfma_f32_32x32x16_bf16(Kf1, Qf1, S, 0, 0, 0);
            // P = exp2(S): regs 0-7 -> PV#1 (keys 0-15), regs 8-15 -> PV#2
            union { bfrag f; unsigned int u[4]; } P1, P2;
            P1.u[0] = pack2h(__builtin_amdgcn_exp2f(S[0]),  __builtin_amdgcn_exp2f(S[1]));
            P1.u[1] = pack2h(__builtin_amdgcn_exp2f(S[2]),  __builtin_amdgcn_exp2f(S[3]));
            P1.u[2] = pack2h(__builtin_amdgcn_exp2f(S[4]),  __builtin_amdgcn_exp2f(S[5]));
            P1.u[3] = pack2h(__builtin_amdgcn_exp2f(S[6]),  __builtin_amdgcn_exp2f(S[7]));
            P2.u[0] = pack2h(__builtin_amdgcn_exp2f(S[8]),  __builtin_amdgcn_exp2f(S[9]));
            P2.u[1] = pack2h(__builtin_amdgcn_exp2f(S[10]), __builtin_amdgcn_exp2f(S[11]));
            P2.u[2] = pack2h(__builtin_amdgcn_exp2f(S[12]), __builtin_amdgcn_exp2f(S[13]));
            P2.u[3] = pack2h(__builtin_amdgcn_exp2f(S[14]), __builtin_amdgcn_exp2f(S[15]));
            // O^T += V^T . P  (A[m=d][k=key], keys natural)
            const bfrag Va0 = *(const bfrag*)(&Vs[q32 * VS_STRIDE + g * 32 + h * 8]);
            const bfrag Va1 = *(const bfrag*)(&Vs[q32 * VS_STRIDE + g * 32 + 16 + h * 8]);
            O = __builtin_amdgcn_mfma_f32_32x32x16_bf16(Va0, P1.f, O, 0, 0, 0);
            O = __builtin_amdgcn_mfma_f32_32x32x16_bf16(Va1, P2.f, O, 0, 0, 0);
        }
        __syncthreads();
    }

    // store fp16 partials: C row=(reg&3)+8*(reg>>2)+4*h = d; col=q32.
    // half0 regs: d {0-3,8-11,16-19,24-27}; half1: d {4-7,12-15,20-23,28-31}.
    const size_t base = ((size_t)split * N_ + qbase + q32) * 32;
    if (h == 0) {
        *(uint2*)(Opart + base +  0) = make_uint2(packh16(O[0], O[1]),  packh16(O[2],  O[3]));
        *(uint2*)(Opart + base +  8) = make_uint2(packh16(O[4], O[5]),  packh16(O[6],  O[7]));
        *(uint2*)(Opart + base + 16) = make_uint2(packh16(O[8], O[9]),  packh16(O[10], O[11]));
        lpart[(size_t)split * N_ + qbase + q32] = O[12];   // d=24 ones-row = l
    } else {
        *(uint2*)(Opart + base +  4) = make_uint2(packh16(O[0], O[1]),  packh16(O[2],  O[3]));
        *(uint2*)(Opart + base + 12) = make_uint2(packh16(O[4], O[5]),  packh16(O[6],  O[7]));
        *(uint2*)(Opart + base + 20) = make_uint2(packh16(O[8], O[9]),  packh16(O[10], O[11]));
    }
}

// ---------------- Kernel 3: combine + output projection ----------------
__global__ __launch_bounds__(256) void combine_kernel(
    const __half* __restrict__ Opart, const float* __restrict__ lpart,
    const unsigned short* __restrict__ wOf, const float* __restrict__ bO,
    float* __restrict__ out, int nsp)
{
    __shared__ unsigned short Hs[64 * HS_STRIDE];

    const int tid = threadIdx.x;
    const int qb  = blockIdx.x * 64;
    {
        const int ql = tid >> 2;
        const int c8 = (tid & 3) * 8;     // dim chunk 0,8,16,24
        const int q  = qb + ql;
        float a[8] = {0.f, 0.f, 0.f, 0.f, 0.f, 0.f, 0.f, 0.f};
        if (c8 < 24) {                    // chunk 24..31 junk -> zeros
            for (int s = 0; s < nsp; ++s) {
                const __half2* p2 = (const __half2*)(Opart + ((size_t)s * N_ + q) * 32 + c8);
                #pragma unroll
                for (int j = 0; j < 4; ++j) {
                    const float2 f = __half22float2(p2[j]);
                    a[2 * j]     += f.x;
                    a[2 * j + 1] += f.y;
                }
            }
        }
        float ls = 0.f;
        for (int s = 0; s < nsp; ++s) ls += lpart[(size_t)s * N_ + q];
        const float inv = 1.0f / ls;
        uint4 pk;
        pk.x = pack2h(a[0] * inv, a[1] * inv);
        pk.y = pack2h(a[2] * inv, a[3] * inv);
        pk.z = pack2h(a[4] * inv, a[5] * inv);
        pk.w = pack2h(a[6] * inv, a[7] * inv);
        *(uint4*)(&Hs[ql * HS_STRIDE + c8]) = pk;
    }
    __syncthreads();

    const int lane = tid & 63;
    const int w    = tid >> 6;
    const int col  = lane & 15;
    const int quad = lane >> 4;
    const bfrag Hf = *(const bfrag*)(&Hs[(w * 16 + col) * HS_STRIDE + quad * 8]);
    #pragma unroll
    for (int nt = 0; nt < 8; ++nt) {
        const bfrag Wo = *(const bfrag*)(wOf + (nt * 64 + lane) * 8);
        ffrag C = {0.f, 0.f, 0.f, 0.f};
        C = __builtin_amdgcn_mfma_f32_16x16x32_bf16(Hf, Wo, C, 0, 0, 0);
        const float bo = bO[nt * 16 + col];
        #pragma unroll
        for (int r = 0; r < 4; ++r)
            out[(size_t)(qb + w * 16 + quad * 4 + r) * 128 + nt * 16 + col] = C[r] + bo;
    }
}

extern "C" void kernel_launch(void* const* d_in, const int* in_sizes, int n_in,
                              void* d_out, int out_size, void* d_ws, size_t ws_size,
                              hipStream_t stream) {
    const float* x  = (const float*)d_in[0];
    const float* wQ = (const float*)d_in[1];
    const float* bQ = (const float*)d_in[2];
    const float* wK = (const float*)d_in[3];
    const float* bK = (const float*)d_in[4];
    const float* wV = (const float*)d_in[5];
    const float* bV = (const float*)d_in[6];
    const float* wO = (const float*)d_in[7];
    const float* bO = (const float*)d_in[8];
    float* out = (float*)d_out;

    unsigned short* ws16 = (unsigned short*)d_ws;
    unsigned short* Qbf = ws16;                                    // N*32 shorts
    unsigned short* Kbf = Qbf + (size_t)N_ * 32;                   // N*32
    unsigned short* Vt  = Kbf + (size_t)N_ * 32;                   // B*24*S
    unsigned short* Wf  = Vt + (size_t)B_ * 24 * S_;               // 10240
    unsigned short* wOf = Wf + 4 * 5 * 512;                        // 4096
    float* bqkv = (float*)(wOf + 8 * 512);                         // 80 fp32
    __half* Opart = (__half*)(bqkv + 80);                          // nsp*N*32 fp16
    const size_t baseBytes = (size_t)((char*)Opart - (char*)d_ws);

    int nsp = 8;
    while (nsp > 1) {
        const size_t need = baseBytes + (size_t)nsp * N_ * 32 * 2 + (size_t)nsp * N_ * 4;
        if (need <= ws_size) break;
        nsp >>= 1;
    }
    float* lpart = (float*)(Opart + (size_t)nsp * N_ * 32);

    prep_kernel<<<8, 256, 0, stream>>>(wQ, bQ, wK, bK, wV, bV, wO, Wf, wOf, bqkv);
    proj_kernel<<<N_ / 64, 256, 0, stream>>>(x, Wf, bqkv, Qbf, Kbf, Vt);
    attn_kernel<<<dim3(N_ / 256, nsp), 512, 0, stream>>>(Qbf, Kbf, Vt, Opart, lpart);
    combine_kernel<<<N_ / 64, 256, 0, stream>>>(Opart, lpart, wOf, bO, out, nsp);
}

// Round 11
// 125.812 us; speedup vs baseline: 1.0178x; 1.0178x over previous
//
#include <hip/hip_runtime.h>
#include <hip/hip_fp16.h>

// MyEncoder: B=8, S=4096, E=128, D=24, fp32 in/out.
// out = softmax((xWq+bq)(xWk+bk)^T / sqrt(128)) (xWv+bv) Wo + bo
// bf16-MFMA pipeline: prep -> proj (QKV GEMM) -> attn (flash partials,
// K-split, 32x32x16 transposed scores, in-register P, MFMA-computed l)
// -> combine (sum fp16 partials + wO epilogue).
// Softmax without max-subtraction (scores tiny, shift-invariant) => K-split
// partials purely additive. exp2 with log2(e) folded into Q scale.
//
// attn (verified r9 on HW): per 32-key group g, keys bit-2<->3-swapped at staging:
//   S^T[key][q] (32x32) = mfma32(K d0-15, Q d0-15) + mfma32(K d16-31, Q d16-31)
//   P = exp2(S^T): C regs 0-7 -> PV#1 B-frag (keys 0-15), regs 8-15 -> PV#2
//   O^T += mfma32(A=V^T natural, B=P); V row d=24 = 1.0 => C reg 12 (h=0) = l.
// r10 change: 256-thread blocks (4 waves) at launch_bounds(256,5) -> 5
// resident blocks/CU (20 waves) instead of r9's 2 blocks (16 waves): barriers
// sync 4 waves and stagger across 5 independent blocks.

#define B_ 8
#define S_ 4096
#define E_ 128
#define D_ 24
#define N_ (B_ * S_)               // 32768 rows
#define SCALE 0.08838834764831845f // 1/sqrt(128)
#define LOG2E 1.4426950408889634f

#define TK 128                     // keys per LDS tile in attn
#define KS_STRIDE 40               // K_s row stride (shorts) = 5x16B (odd -> conflict-free)
#define VS_STRIDE 136              // V_s row stride (shorts) = 17x16B (odd -> conflict-free)
#define HS_STRIDE 40               // H_s row stride in combine
#define XS_STRIDE 136              // x_s row stride (bf16) in proj
#define OS_STRIDE 84               // out_s row stride (fp32) in proj

typedef __attribute__((ext_vector_type(8))) short bfrag;    // 8 bf16 = 4 VGPR
typedef __attribute__((ext_vector_type(4))) float ffrag;    // 4 fp32
typedef __attribute__((ext_vector_type(16))) float ffrag16; // 16 fp32 (32x32 C)

__device__ inline unsigned short f2bf(float f) {           // RNE fp32->bf16
    unsigned int x = __builtin_bit_cast(unsigned int, f);
    return (unsigned short)((x + 0x7fffu + ((x >> 16) & 1u)) >> 16);
}
// round-half-up bf16 pair pack: 2 int-adds + v_perm (validated r5-r9 on HW)
__device__ inline unsigned int pack2h(float a, float b) {
    unsigned int ua = __builtin_bit_cast(unsigned int, a) + 0x8000u;
    unsigned int ub = __builtin_bit_cast(unsigned int, b) + 0x8000u;
    return __builtin_amdgcn_perm(ub, ua, 0x07060302);      // [a.hi16 | b.hi16]
}
// fp16 pair pack, RTZ, single v_cvt_pkrtz_f16_f32
__device__ inline unsigned int packh16(float a, float b) {
    return __builtin_bit_cast(unsigned int, __builtin_amdgcn_cvt_pkrtz(a, b));
}

// ---------------- Kernel 0: weight prep (8 blocks) ----------------
__global__ __launch_bounds__(256) void prep_kernel(
    const float* __restrict__ wQ, const float* __restrict__ bQ,
    const float* __restrict__ wK, const float* __restrict__ bK,
    const float* __restrict__ wV, const float* __restrict__ bV,
    const float* __restrict__ wO,
    unsigned short* __restrict__ Wf, unsigned short* __restrict__ wOf,
    float* __restrict__ bqkv)
{
    const int gtid   = blockIdx.x * 256 + threadIdx.x;
    const int stride = gridDim.x * 256;
    const float qs = SCALE * LOG2E;
    for (int idx = gtid; idx < 4 * 5 * 512; idx += stride) {
        const int j    = idx & 7;
        const int lane = (idx >> 3) & 63;
        const int nt   = (idx >> 9) % 5;
        const int kt   = idx / 2560;
        const int n = nt * 16 + (lane & 15);
        const int k = kt * 32 + ((lane >> 4) << 3) + j;
        float v = 0.0f;
        if (n < 24)      v = wQ[k * 24 + n] * qs;
        else if (n < 48) v = wK[k * 24 + (n - 24)];
        else if (n < 72) v = wV[k * 24 + (n - 48)];
        Wf[idx] = f2bf(v);
    }
    for (int idx = gtid; idx < 8 * 512; idx += stride) {
        const int j    = idx & 7;
        const int lane = (idx >> 3) & 63;
        const int nt   = idx >> 9;
        const int k = ((lane >> 4) << 3) + j;
        const int e = nt * 16 + (lane & 15);
        wOf[idx] = (k < 24) ? f2bf(wO[k * 128 + e]) : (unsigned short)0;
    }
    if (gtid < 80) {
        float v = 0.0f;
        if (gtid < 24)      v = bQ[gtid] * qs;
        else if (gtid < 48) v = bK[gtid - 24];
        else if (gtid < 72) v = bV[gtid - 48];
        bqkv[gtid] = v;
    }
}

// ---------------- Kernel 1: QKV projection (MFMA) ----------------
__global__ __launch_bounds__(256) void proj_kernel(
    const float* __restrict__ x, const unsigned short* __restrict__ Wf,
    const float* __restrict__ bqkv,
    unsigned short* __restrict__ Qbf, unsigned short* __restrict__ Kbf,
    unsigned short* __restrict__ Vt)
{
    __shared__ float smem[64 * OS_STRIDE];          // 21504 B, dual-purpose
    unsigned short* xs = (unsigned short*)smem;     // [64][XS_STRIDE]
    float* os = smem;                               // [64][OS_STRIDE]

    const int tid  = threadIdx.x;
    const int lane = tid & 63;
    const int w    = tid >> 6;
    const int col  = lane & 15;
    const int quad = lane >> 4;
    const int rb   = blockIdx.x * 64;

    #pragma unroll
    for (int i = 0; i < 8; ++i) {
        const int idx = i * 256 + tid;
        const int row = idx >> 5, c4 = idx & 31;
        const float4 xv = *(const float4*)(x + (size_t)(rb + row) * 128 + c4 * 4);
        uint2 h;
        h.x = pack2h(xv.x, xv.y);
        h.y = pack2h(xv.z, xv.w);
        *(uint2*)(&xs[row * XS_STRIDE + c4 * 4]) = h;
    }

    bfrag Wfr[20];
    #pragma unroll
    for (int f = 0; f < 20; ++f)
        Wfr[f] = *(const bfrag*)(Wf + (f * 64 + lane) * 8);

    __syncthreads();

    ffrag acc[5];
    #pragma unroll
    for (int nt = 0; nt < 5; ++nt) acc[nt] = (ffrag){0.f, 0.f, 0.f, 0.f};

    #pragma unroll
    for (int kt = 0; kt < 4; ++kt) {
        const bfrag Af = *(const bfrag*)(&xs[(w * 16 + col) * XS_STRIDE + kt * 32 + quad * 8]);
        #pragma unroll
        for (int nt = 0; nt < 5; ++nt)
            acc[nt] = __builtin_amdgcn_mfma_f32_16x16x32_bf16(Af, Wfr[kt * 5 + nt], acc[nt], 0, 0, 0);
    }

    __syncthreads();

    #pragma unroll
    for (int nt = 0; nt < 5; ++nt) {
        const float bb = bqkv[nt * 16 + col];
        #pragma unroll
        for (int r = 0; r < 4; ++r)
            os[(w * 16 + quad * 4 + r) * OS_STRIDE + nt * 16 + col] = acc[nt][r] + bb;
    }
    __syncthreads();

    // Q (tid<128) / K (tid>=128): row-major bf16, cols padded to 32
    {
        const int half  = tid & 1;
        const int row   = (tid >> 1) & 63;
        const int isK   = tid >> 7;
        const int cbase = isK * 24;
        unsigned int pk[8];
        #pragma unroll
        for (int g = 0; g < 8; ++g) {
            const int c0 = half * 16 + g * 2;
            const float f0 = (c0     < 24) ? os[row * OS_STRIDE + cbase + c0]     : 0.0f;
            const float f1 = (c0 + 1 < 24) ? os[row * OS_STRIDE + cbase + c0 + 1] : 0.0f;
            pk[g] = pack2h(f0, f1);
        }
        unsigned short* dst = (isK ? Kbf : Qbf) + (size_t)(rb + row) * 32 + half * 16;
        *(uint4*)(dst)     = make_uint4(pk[0], pk[1], pk[2], pk[3]);
        *(uint4*)(dst + 8) = make_uint4(pk[4], pk[5], pk[6], pk[7]);
    }

    // Vt: transposed [b][d][s], 16B stores
    if (tid < 192) {
        const int d  = tid % 24;
        const int ch = tid / 24;
        unsigned int p[4];
        #pragma unroll
        for (int g = 0; g < 4; ++g) {
            const float f0 = os[(ch * 8 + g * 2 + 0) * OS_STRIDE + 48 + d];
            const float f1 = os[(ch * 8 + g * 2 + 1) * OS_STRIDE + 48 + d];
            p[g] = pack2h(f0, f1);
        }
        const int b = rb >> 12, s0 = rb & 4095;
        uint4* dst = (uint4*)(Vt + (((size_t)(b * 24 + d)) << 12) + s0 + ch * 8);
        *dst = make_uint4(p[0], p[1], p[2], p[3]);
    }
}

// ---------------- Kernel 2: flash attention partials (32x32x16) ----------
// Grid (N/128, nsp). 256 threads = 4 waves x 32 queries = 128 q/block.
// launch_bounds(256,5): ~90-VGPR body -> 5 resident blocks/CU, 20 waves.
__global__ __launch_bounds__(256, 5) void attn_kernel(
    const unsigned short* __restrict__ Qbf, const unsigned short* __restrict__ Kbf,
    const unsigned short* __restrict__ Vt,
    __half* __restrict__ Opart, float* __restrict__ lpart)
{
    __shared__ unsigned short Ks[TK * KS_STRIDE];     // 10240 B
    __shared__ unsigned short Vs[32 * VS_STRIDE];     // 8704 B (rows 25-31 junk, contained)

    const int tid    = threadIdx.x;
    const int lane   = tid & 63;
    const int w      = tid >> 6;                      // 0..3
    const int q32    = lane & 31;                     // q within tile; also m-row idx
    const int h      = lane >> 5;                     // half
    const int blk    = blockIdx.x;                    // 0..N/128-1
    const int split  = blockIdx.y;
    const int nsp    = gridDim.y;
    const int kchunk = S_ / nsp;
    const int b      = blk >> 5;                      // 32 blocks per batch
    const int qbase  = blk * 128 + w * 32;

    // ones row d=24 (128 keys = 16 uint4); staging only touches rows 0..23
    if (tid < 16)
        *(uint4*)(&Vs[24 * VS_STRIDE + tid * 8]) =
            make_uint4(0x3F803F80u, 0x3F803F80u, 0x3F803F80u, 0x3F803F80u);

    // Q B-frags: B[k=d][n=q]: n=lane&31, k=h*8+j (+16 for second MFMA)
    const bfrag Qf0 = *(const bfrag*)(Qbf + (size_t)(qbase + q32) * 32 + h * 8);
    const bfrag Qf1 = *(const bfrag*)(Qbf + (size_t)(qbase + q32) * 32 + 16 + h * 8);

    ffrag16 O = {0.f,0.f,0.f,0.f,0.f,0.f,0.f,0.f,0.f,0.f,0.f,0.f,0.f,0.f,0.f,0.f};

    const unsigned short* Kbase = Kbf + ((size_t)(b * 4096) + split * kchunk) * 32;
    const unsigned short* Vbase = Vt + (size_t)(b * 24) * 4096 + split * kchunk;

    __syncthreads();   // ones row visible

    for (int kb = 0; kb < kchunk; kb += TK) {
        // K tile: key -> row swap of bits 2,3 within each 32-key group
        #pragma unroll
        for (int i = 0; i < 2; ++i) {
            const int idx = i * 256 + tid;            // 0..511
            const int key = idx >> 2, ch = idx & 3;
            const uint4 t4 = *(const uint4*)(Kbase + (size_t)(kb + key) * 32 + ch * 8);
            const int kl  = key & 31;
            const int row = (key & ~31) | (kl & 19) | ((kl & 4) << 1) | ((kl & 8) >> 1);
            *(uint4*)(&Ks[row * KS_STRIDE + ch * 8]) = t4;
        }
        // V tile: 24 d-rows x 128 keys, natural order (384 uint4)
        #pragma unroll
        for (int i = 0; i < 2; ++i) {
            const int u = i * 256 + tid;
            if (u < 384) {
                const int d = u >> 4, ch = u & 15;
                const uint4 t4 = *(const uint4*)(Vbase + (size_t)d * 4096 + kb + ch * 8);
                *(uint4*)(&Vs[d * VS_STRIDE + ch * 8]) = t4;
            }
        }
        __syncthreads();

        #pragma unroll
        for (int g = 0; g < 4; ++g) {
            // S^T (32 keys x 32 q): A[m=key-row][k=d] = Ks, two d-halves
            const bfrag Kf0 = *(const bfrag*)(&Ks[(g * 32 + q32) * KS_STRIDE + h * 8]);
            const bfrag Kf1 = *(const bfrag*)(&Ks[(g * 32 + q32) * KS_STRIDE + 16 + h * 8]);
            ffrag16 S = {0.f,0.f,0.f,0.f,0.f,0.f,0.f,0.f,0.f,0.f,0.f,0.f,0.f,0.f,0.f,0.f};
            S = __builtin_amdgcn_mfma_f32_32x32x16_bf16(Kf0, Qf0, S, 0, 0, 0);
            S = __builtin_amdgcn_mfma_f32_32x32x16_bf16(Kf1, Qf1, S, 0, 0, 0);
            // P = exp2(S): regs 0-7 -> PV#1 (keys 0-15), regs 8-15 -> PV#2
            union { bfrag f; unsigned int u[4]; } P1, P2;
            P1.u[0] = pack2h(__builtin_amdgcn_exp2f(S[0]),  __builtin_amdgcn_exp2f(S[1]));
            P1.u[1] = pack2h(__builtin_amdgcn_exp2f(S[2]),  __builtin_amdgcn_exp2f(S[3]));
            P1.u[2] = pack2h(__builtin_amdgcn_exp2f(S[4]),  __builtin_amdgcn_exp2f(S[5]));
            P1.u[3] = pack2h(__builtin_amdgcn_exp2f(S[6]),  __builtin_amdgcn_exp2f(S[7]));
            P2.u[0] = pack2h(__builtin_amdgcn_exp2f(S[8]),  __builtin_amdgcn_exp2f(S[9]));
            P2.u[1] = pack2h(__builtin_amdgcn_exp2f(S[10]), __builtin_amdgcn_exp2f(S[11]));
            P2.u[2] = pack2h(__builtin_amdgcn_exp2f(S[12]), __builtin_amdgcn_exp2f(S[13]));
            P2.u[3] = pack2h(__builtin_amdgcn_exp2f(S[14]), __builtin_amdgcn_exp2f(S[15]));
            // O^T += V^T . P  (A[m=d][k=key], keys natural)
            const bfrag Va0 = *(const bfrag*)(&Vs[q32 * VS_STRIDE + g * 32 + h * 8]);
            const bfrag Va1 = *(const bfrag*)(&Vs[q32 * VS_STRIDE + g * 32 + 16 + h * 8]);
            O = __builtin_amdgcn_mfma_f32_32x32x16_bf16(Va0, P1.f, O, 0, 0, 0);
            O = __builtin_amdgcn_mfma_f32_32x32x16_bf16(Va1, P2.f, O, 0, 0, 0);
        }
        __syncthreads();
    }

    // store fp16 partials: C row=(reg&3)+8*(reg>>2)+4*h = d; col=q32.
    // half0 regs: d {0-3,8-11,16-19,24-27}; half1: d {4-7,12-15,20-23,28-31}.
    const size_t base = ((size_t)split * N_ + qbase + q32) * 32;
    if (h == 0) {
        *(uint2*)(Opart + base +  0) = make_uint2(packh16(O[0], O[1]),  packh16(O[2],  O[3]));
        *(uint2*)(Opart + base +  8) = make_uint2(packh16(O[4], O[5]),  packh16(O[6],  O[7]));
        *(uint2*)(Opart + base + 16) = make_uint2(packh16(O[8], O[9]),  packh16(O[10], O[11]));
        lpart[(size_t)split * N_ + qbase + q32] = O[12];   // d=24 ones-row = l
    } else {
        *(uint2*)(Opart + base +  4) = make_uint2(packh16(O[0], O[1]),  packh16(O[2],  O[3]));
        *(uint2*)(Opart + base + 12) = make_uint2(packh16(O[4], O[5]),  packh16(O[6],  O[7]));
        *(uint2*)(Opart + base + 20) = make_uint2(packh16(O[8], O[9]),  packh16(O[10], O[11]));
    }
}

// ---------------- Kernel 3: combine + output projection ----------------
__global__ __launch_bounds__(256) void combine_kernel(
    const __half* __restrict__ Opart, const float* __restrict__ lpart,
    const unsigned short* __restrict__ wOf, const float* __restrict__ bO,
    float* __restrict__ out, int nsp)
{
    __shared__ unsigned short Hs[64 * HS_STRIDE];

    const int tid = threadIdx.x;
    const int qb  = blockIdx.x * 64;
    {
        const int ql = tid >> 2;
        const int c8 = (tid & 3) * 8;     // dim chunk 0,8,16,24
        const int q  = qb + ql;
        float a[8] = {0.f, 0.f, 0.f, 0.f, 0.f, 0.f, 0.f, 0.f};
        if (c8 < 24) {                    // chunk 24..31 junk -> zeros
            for (int s = 0; s < nsp; ++s) {
                const __half2* p2 = (const __half2*)(Opart + ((size_t)s * N_ + q) * 32 + c8);
                #pragma unroll
                for (int j = 0; j < 4; ++j) {
                    const float2 f = __half22float2(p2[j]);
                    a[2 * j]     += f.x;
                    a[2 * j + 1] += f.y;
                }
            }
        }
        float ls = 0.f;
        for (int s = 0; s < nsp; ++s) ls += lpart[(size_t)s * N_ + q];
        const float inv = 1.0f / ls;
        uint4 pk;
        pk.x = pack2h(a[0] * inv, a[1] * inv);
        pk.y = pack2h(a[2] * inv, a[3] * inv);
        pk.z = pack2h(a[4] * inv, a[5] * inv);
        pk.w = pack2h(a[6] * inv, a[7] * inv);
        *(uint4*)(&Hs[ql * HS_STRIDE + c8]) = pk;
    }
    __syncthreads();

    const int lane = tid & 63;
    const int w    = tid >> 6;
    const int col  = lane & 15;
    const int quad = lane >> 4;
    const bfrag Hf = *(const bfrag*)(&Hs[(w * 16 + col) * HS_STRIDE + quad * 8]);
    #pragma unroll
    for (int nt = 0; nt < 8; ++nt) {
        const bfrag Wo = *(const bfrag*)(wOf + (nt * 64 + lane) * 8);
        ffrag C = {0.f, 0.f, 0.f, 0.f};
        C = __builtin_amdgcn_mfma_f32_16x16x32_bf16(Hf, Wo, C, 0, 0, 0);
        const float bo = bO[nt * 16 + col];
        #pragma unroll
        for (int r = 0; r < 4; ++r)
            out[(size_t)(qb + w * 16 + quad * 4 + r) * 128 + nt * 16 + col] = C[r] + bo;
    }
}

extern "C" void kernel_launch(void* const* d_in, const int* in_sizes, int n_in,
                              void* d_out, int out_size, void* d_ws, size_t ws_size,
                              hipStream_t stream) {
    const float* x  = (const float*)d_in[0];
    const float* wQ = (const float*)d_in[1];
    const float* bQ = (const float*)d_in[2];
    const float* wK = (const float*)d_in[3];
    const float* bK = (const float*)d_in[4];
    const float* wV = (const float*)d_in[5];
    const float* bV = (const float*)d_in[6];
    const float* wO = (const float*)d_in[7];
    const float* bO = (const float*)d_in[8];
    float* out = (float*)d_out;

    unsigned short* ws16 = (unsigned short*)d_ws;
    unsigned short* Qbf = ws16;                                    // N*32 shorts
    unsigned short* Kbf = Qbf + (size_t)N_ * 32;                   // N*32
    unsigned short* Vt  = Kbf + (size_t)N_ * 32;                   // B*24*S
    unsigned short* Wf  = Vt + (size_t)B_ * 24 * S_;               // 10240
    unsigned short* wOf = Wf + 4 * 5 * 512;                        // 4096
    float* bqkv = (float*)(wOf + 8 * 512);                         // 80 fp32
    __half* Opart = (__half*)(bqkv + 80);                          // nsp*N*32 fp16
    const size_t baseBytes = (size_t)((char*)Opart - (char*)d_ws);

    int nsp = 8;
    while (nsp > 1) {
        const size_t need = baseBytes + (size_t)nsp * N_ * 32 * 2 + (size_t)nsp * N_ * 4;
        if (need <= ws_size) break;
        nsp >>= 1;
    }
    float* lpart = (float*)(Opart + (size_t)nsp * N_ * 32);

    prep_kernel<<<8, 256, 0, stream>>>(wQ, bQ, wK, bK, wV, bV, wO, Wf, wOf, bqkv);
    proj_kernel<<<N_ / 64, 256, 0, stream>>>(x, Wf, bqkv, Qbf, Kbf, Vt);
    attn_kernel<<<dim3(N_ / 128, nsp), 256, 0, stream>>>(Qbf, Kbf, Vt, Opart, lpart);
    combine_kernel<<<N_ / 64, 256, 0, stream>>>(Opart, lpart, wOf, bO, out, nsp);
}